// Round 1
// 31.111 us; speedup vs baseline: 1.0325x; 1.0325x over previous
//
#include <hip/hip_runtime.h>
#include <math.h>

#define IMG_H  384
#define IMG_W  384
#define IMG_HW (IMG_H * IMG_W)
#define NB     4
#define NC     3
#define NK     48
#define NH     24          /* taps per lane-half */

struct PosAdd { float v[NK]; };

__global__ __launch_bounds__(256) void LLA_41412074668179_kernel(
    const float* __restrict__ imgs, float* __restrict__ out, PosAdd pa)
{
    const int tid  = threadIdx.x;
    const int lane = tid & 63;
    const int t    = lane >> 5;              // 0 -> dil{1,2,4}=k0..23, 1 -> dil{8,12,24}=k24..47

    // XCD-chunked swizzle: hardware round-robins blockIdx%8 -> XCD.
    // grid = 4608 = 8 * 576; give each XCD a contiguous 576-block chunk
    // (= 192 consecutive image rows) so the +/-24-row tap reuse stays in
    // that XCD's private 4 MiB L2 instead of thrashing through L3.
    const int lb = (blockIdx.x & 7) * 576 + (blockIdx.x >> 3);

    // half-wave (32 lanes) covers 32 consecutive pixels; both halves same pixels
    const int px   = lb * 128 + (tid >> 6) * 32 + (lane & 31);
    const int w  = px % IMG_W;
    const int hb = px / IMG_W;
    const int h  = hb % IMG_H;
    const int b  = hb / IMG_H;

    const int dils[3] = { t ? 8 : 1, t ? 12 : 2, t ? 24 : 4 };

    const int r0 = h * IMG_W;
    int rm[3], rp[3], cm[3], cp[3];
#pragma unroll
    for (int di = 0; di < 3; ++di) {
        const int d = dils[di];
        rm[di] = max(h - d, 0) * IMG_W;
        rp[di] = min(h + d, IMG_H - 1) * IMG_W;
        cm[di] = max(w - d, 0);
        cp[di] = min(w + d, IMG_W - 1);
    }

    float acc[NH];
#pragma unroll
    for (int j = 0; j < NH; ++j) acc[j] = 0.0f;

#pragma unroll
    for (int c = 0; c < NC; ++c) {
        const float* __restrict__ pc = imgs + ((size_t)b * NC + c) * IMG_HW;
        const float x = pc[r0 + w];

        float nbv[NH];
#pragma unroll
        for (int di = 0; di < 3; ++di) {
            nbv[di*8+0] = pc[rm[di] + cm[di]];
            nbv[di*8+1] = pc[rm[di] + w];
            nbv[di*8+2] = pc[rm[di] + cp[di]];
            nbv[di*8+3] = pc[r0     + cm[di]];
            nbv[di*8+4] = pc[r0     + cp[di]];
            nbv[di*8+5] = pc[rp[di] + cm[di]];
            nbv[di*8+6] = pc[rp[di] + w];
            nbv[di*8+7] = pc[rp[di] + cp[di]];
        }

        // partial stats over my 24 taps; combine across lane-halves -> all 48
        float s0 = 0.0f, s1 = 0.0f, q0 = 0.0f, q1 = 0.0f;
#pragma unroll
        for (int j = 0; j < NH; j += 2) {
            s0 += nbv[j];
            s1 += nbv[j+1];
            q0 = fmaf(nbv[j],   nbv[j],   q0);
            q1 = fmaf(nbv[j+1], nbv[j+1], q1);
        }
        float s  = s0 + s1;
        float ss = q0 + q1;
        s  += __shfl_xor(s, 32);
        ss += __shfl_xor(ss, 32);

        const float mean = s * (1.0f / 48.0f);
        const float var  = fmaxf((ss - s * mean) * (1.0f / 47.0f), 0.0f);
        const float scl  = __builtin_amdgcn_rcpf(
                               fmaf(__builtin_amdgcn_sqrtf(var), 0.3f, 3.0e-9f));
        const float xs = x * scl;

#pragma unroll
        for (int j = 0; j < NH; ++j) {
            const float d = fmaf(nbv[j], scl, -xs);   // (v-x)*scl in one fma
            acc[j] = fmaf(d, d, acc[j]);
        }
    }

    // softmax over all 48: max(aff) == min(acc); cross-half via shfl
    float m0 = fminf(acc[0], acc[1]), m1 = fminf(acc[2], acc[3]);
    float m2 = fminf(acc[4], acc[5]), m3 = fminf(acc[6], acc[7]);
#pragma unroll
    for (int j = 8; j < NH; j += 8) {
        m0 = fminf(m0, fminf(acc[j+0], acc[j+1]));
        m1 = fminf(m1, fminf(acc[j+2], acc[j+3]));
        m2 = fminf(m2, fminf(acc[j+4], acc[j+5]));
        m3 = fminf(m3, fminf(acc[j+6], acc[j+7]));
    }
    float mn = fminf(fminf(m0, m1), fminf(m2, m3));
    mn = fminf(mn, __shfl_xor(mn, 32));

    const float SC   = (1.0f / 3.0f) * 1.44269504f;   // /3 then ln->log2
    const float mnSC = mn * SC;
    float e0 = 0.0f, e1 = 0.0f, e2 = 0.0f, e3 = 0.0f;
#pragma unroll
    for (int j = 0; j < NH; j += 4) {
        acc[j+0] = __builtin_amdgcn_exp2f(fmaf(acc[j+0], -SC, mnSC));
        acc[j+1] = __builtin_amdgcn_exp2f(fmaf(acc[j+1], -SC, mnSC));
        acc[j+2] = __builtin_amdgcn_exp2f(fmaf(acc[j+2], -SC, mnSC));
        acc[j+3] = __builtin_amdgcn_exp2f(fmaf(acc[j+3], -SC, mnSC));
        e0 += acc[j+0]; e1 += acc[j+1]; e2 += acc[j+2]; e3 += acc[j+3];
    }
    float se = (e0 + e1) + (e2 + e3);
    se += __shfl_xor(se, 32);
    const float inv = __builtin_amdgcn_rcpf(se);

    float* __restrict__ op = out + ((size_t)(b * NK + t * NH)) * IMG_HW + r0 + w;
#pragma unroll
    for (int j = 0; j < NH; ++j) {
        const float pav = t ? pa.v[NH + j] : pa.v[j];
        __builtin_nontemporal_store(fmaf(acc[j], inv, pav),
                                    op + (size_t)j * IMG_HW);
    }
}

static void compute_pos_add(float* out48)
{
    const int DIL[6] = {1, 2, 4, 8, 12, 24};
    const double SQ2 = 1.4142135623730951;
    const double diag[8] = {SQ2, 1.0, SQ2, 1.0, 1.0, SQ2, 1.0, SQ2};

    double pos[NK];
    for (int di = 0; di < 6; ++di)
        for (int tp = 0; tp < 8; ++tp)
            pos[di * 8 + tp] = (double)((float)(diag[tp] * DIL[di]));  // match fp32 concat

    double s = 0.0;
    for (int k = 0; k < NK; ++k) s += pos[k];
    const double m = s / NK;
    double v = 0.0;
    for (int k = 0; k < NK; ++k) { const double d = pos[k] - m; v += d * d; }
    v /= (NK - 1);
    const double stdv = sqrt(v);

    double aff[NK];
    double mx = -1e300;
    for (int k = 0; k < NK; ++k) {
        const double q = pos[k] / ((stdv + 1e-8) * 0.3);
        aff[k] = -(q * q);
        if (aff[k] > mx) mx = aff[k];
    }
    double se = 0.0;
    for (int k = 0; k < NK; ++k) { aff[k] = exp(aff[k] - mx); se += aff[k]; }
    for (int k = 0; k < NK; ++k) out48[k] = (float)(0.01 * aff[k] / se);
}

extern "C" void kernel_launch(void* const* d_in, const int* in_sizes, int n_in,
                              void* d_out, int out_size, void* d_ws, size_t ws_size,
                              hipStream_t stream)
{
    const float* imgs = (const float*)d_in[0];
    float* out = (float*)d_out;

    PosAdd pa;
    compute_pos_add(pa.v);

    // 2 thread-slots per pixel (k-split across lane halves)
    const int blocks = (NB * IMG_H * IMG_W * 2) / 256;   // 4608
    LLA_41412074668179_kernel<<<blocks, 256, 0, stream>>>(imgs, out, pa);
}